// Round 14
// baseline (252.341 us; speedup 1.0000x reference)
//
#include <hip/hip_runtime.h>

#define NB   32
#define CIN  32
#define PL   192
#define CP   96        // channel pairs (PL/2)
#define NG1  4         // 8-ch groups in conv1 input (32/8)
#define NG3  24        // 8-ch groups in conv3 input (192/8)
#define HH   112
#define WID  112
#define HW   12544     // 112*112
#define COUT 32
#define PXB  1568      // NB*HW/256
#define SEG8 14        // WID/8
#define RT8  784       // (HH/2)*(WID/8) row-pair x 8px tiles per (n,G)

// ws u32-offset layout
#define W2NOFF 64                       // 768 u32: per ch-pair 8 dwords {c0r0,c1r0,c0r1,c1r1,c0r2,c1r2,0,0}
#define W1NOFF (W2NOFF + CP*8)          // 768 u32: w1 8-ch nibble words [g=4][192]
#define W3NOFF (W1NOFF + NG1*PL)        // 768 u32: w3 8-ch nibble words [g=24][32]
#define Q1OFF_BYTES 65536
#define QBYTES ((size_t)NB*CP*HW)       // 38,535,168 bytes per packed tensor
// scalars: wsi[0..3]=absmax bits x,w1,w2,w3; wsi[4]=conv1 int max; wsi[5]=conv2 int max
//         wsi[8]=last-block counter (zeroed by memset each call)

__device__ __forceinline__ int sdot8(unsigned int a, unsigned int b, int c) {
#if defined(__has_builtin) && __has_builtin(__builtin_amdgcn_sdot8)
  return __builtin_amdgcn_sdot8((int)a, (int)b, c, false);
#else
#pragma unroll
  for (int i = 0; i < 8; ++i)
    c += ((int)(a << (28 - 4 * i)) >> 28) * ((int)(b << (28 - 4 * i)) >> 28);
  return c;
#endif
}

// 4-byte sliding window: ((lo>>8*SH)|(hi<<(32-8*SH))) via v_perm
template <int SH>
__device__ __forceinline__ unsigned int winsh(unsigned int hi, unsigned int lo) {
#if defined(__has_builtin) && __has_builtin(__builtin_amdgcn_perm)
  const unsigned int sel = (SH == 1) ? 0x04030201u : (SH == 2) ? 0x05040302u : 0x06050403u;
  return __builtin_amdgcn_perm(hi, lo, sel);
#else
  return (lo >> (8 * SH)) | (hi << (32 - 8 * SH));
#endif
}

__device__ __forceinline__ float quant87(float v, float s) {
  return fminf(fmaxf(rintf(v / s), -8.0f), 7.0f);
}

__device__ __forceinline__ float scl(int bits) {
  return fmaxf(__int_as_float(bits) / 7.0f, 1e-8f);
}

// block-level int max -> single conditional atomic (monotone max: race-safe)
__device__ __forceinline__ void block_max_commit(int lmax, int* __restrict__ slot) {
  __shared__ int red[4];
  for (int o = 32; o; o >>= 1) lmax = max(lmax, __shfl_down(lmax, o));
  if ((threadIdx.x & 63) == 0) red[threadIdx.x >> 6] = lmax;
  __syncthreads();
  if (threadIdx.x == 0) {
    int m = max(max(red[0], red[1]), max(red[2], red[3]));
    int cur = *(const volatile int*)slot;
    if (m > cur) atomicMax(slot, m);
  }
}

// merged absmax (blocks 0..1023 -> x; 1024..1026 -> w1/w2/w3) + last-block
// weight-table prep (all maxes final & visible via fence+counter).
__global__ void kmax_prep(const float* __restrict__ x, int n4,
                          const float* __restrict__ w1, const float* __restrict__ w2,
                          const float* __restrict__ w3, int* __restrict__ wsi,
                          unsigned int* __restrict__ wsu) {
  float m = 0.f;
  int slot;
  if (blockIdx.x < 1024) {
    const float4* x4 = (const float4*)x;
    for (int i = blockIdx.x * blockDim.x + threadIdx.x; i < n4; i += 1024 * blockDim.x) {
      float4 v = x4[i];
      m = fmaxf(fmaxf(fabsf(v.x), fabsf(v.y)), fmaxf(fmaxf(fabsf(v.z), fabsf(v.w)), m));
    }
    slot = 0;
  } else {
    const float* p; int n;
    int w = blockIdx.x - 1024;
    if (w == 0)      { p = w1; n = PL * CIN; }
    else if (w == 1) { p = w2; n = PL * 9; }
    else             { p = w3; n = COUT * PL; }
    for (int i = threadIdx.x; i < n; i += blockDim.x) m = fmaxf(m, fabsf(p[i]));
    slot = 1 + w;
  }
  block_max_commit(__float_as_int(m), wsi + slot);   // non-negative: int cmp == float cmp

  // last-block-done: the finisher sees all committed maxes and builds tables
  __shared__ int amLast;
  __threadfence();                      // my atomicMax visible before counter inc
  if (threadIdx.x == 0)
    amLast = (atomicAdd(wsi + 8, 1) == (int)gridDim.x - 1);
  __syncthreads();
  if (!amLast) return;

  float sw1 = scl(*(volatile int*)(wsi + 1));
  float sw2 = scl(*(volatile int*)(wsi + 2));
  float sw3 = scl(*(volatile int*)(wsi + 3));
  // w1 8-ch nibble words [g][192]
  for (int i = threadIdx.x; i < NG1 * PL; i += blockDim.x) {
    int g = i / PL, o = i - g * PL;
    unsigned int wrd = 0;
    for (int j = 0; j < 8; ++j)
      wrd |= ((unsigned)((int)quant87(w1[o * CIN + 8 * g + j], sw1) & 15)) << (4 * j);
    wsu[W1NOFF + i] = wrd;
  }
  // w2 nibble-slotted dual-channel row words
  for (int cp = threadIdx.x; cp < CP; cp += blockDim.x) {
    unsigned int d[8];
    for (int R = 0; R < 3; ++R) {
      int a0 = (int)quant87(w2[(2 * cp) * 9 + 3 * R],     sw2) & 15;
      int a1 = (int)quant87(w2[(2 * cp) * 9 + 3 * R + 1], sw2) & 15;
      int a2 = (int)quant87(w2[(2 * cp) * 9 + 3 * R + 2], sw2) & 15;
      int b0 = (int)quant87(w2[(2 * cp + 1) * 9 + 3 * R],     sw2) & 15;
      int b1 = (int)quant87(w2[(2 * cp + 1) * 9 + 3 * R + 1], sw2) & 15;
      int b2 = (int)quant87(w2[(2 * cp + 1) * 9 + 3 * R + 2], sw2) & 15;
      d[2 * R]     = (unsigned)(a0 | (a1 << 8) | (a2 << 16));
      d[2 * R + 1] = (unsigned)((b0 << 4) | (b1 << 12) | (b2 << 20));
    }
    d[6] = 0u; d[7] = 0u;
    for (int k = 0; k < 8; ++k) wsu[W2NOFF + cp * 8 + k] = d[k];
  }
  // w3 8-ch nibble words [g][32]
  for (int i = threadIdx.x; i < NG3 * COUT; i += blockDim.x) {
    int g = i / COUT, o = i - g * COUT;
    unsigned int wrd = 0;
    for (int j = 0; j < 8; ++j)
      wrd |= ((unsigned)((int)quant87(w3[o * PL + 8 * g + j], sw3) & 15)) << (4 * j);
    wsu[W3NOFF + i] = wrd;
  }
}

// fused: quantize x (1 px x 32 ch, in regs) -> write xq4 + conv1 global max.
__launch_bounds__(256)
__global__ void kqx1(const float* __restrict__ x, const unsigned int* __restrict__ wsu,
                     int* __restrict__ wsi, unsigned int* __restrict__ xq4,
                     int* __restrict__ maxslot) {
  __shared__ unsigned int lw[NG1 * PL];   // [g][192]
  float sx = scl(wsi[0]);
#pragma unroll
  for (int k = 0; k < 3; ++k)
    lw[threadIdx.x + k * 256] = wsu[W1NOFF + threadIdx.x + k * 256];
  __syncthreads();
  int gp = blockIdx.x * 256 + threadIdx.x;   // blocks never straddle n
  int n = gp / HW, pos = gp - n * HW;
  const float* xp = x + (size_t)n * CIN * HW + pos;
  unsigned int xv[NG1];
#pragma unroll
  for (int g = 0; g < NG1; ++g) {
    unsigned int wrd = 0;
#pragma unroll
    for (int j = 0; j < 8; ++j) {
      float v = xp[(size_t)(8 * g + j) * HW];
      wrd |= ((unsigned)((int)quant87(v, sx) & 15)) << (4 * j);
    }
    xv[g] = wrd;
    xq4[((size_t)n * NG1 + g) * HW + pos] = wrd;
  }
  int lmax = 0;
#pragma unroll 4
  for (int o = 0; o < PL; o += 4) {
    uint4 wg0 = *(const uint4*)&lw[o];
    uint4 wg1 = *(const uint4*)&lw[PL + o];
    uint4 wg2 = *(const uint4*)&lw[2 * PL + o];
    uint4 wg3 = *(const uint4*)&lw[3 * PL + o];
    int a0 = sdot8(xv[3], wg3.x, sdot8(xv[2], wg2.x, sdot8(xv[1], wg1.x, sdot8(xv[0], wg0.x, 0))));
    int a1 = sdot8(xv[3], wg3.y, sdot8(xv[2], wg2.y, sdot8(xv[1], wg1.y, sdot8(xv[0], wg0.y, 0))));
    int a2 = sdot8(xv[3], wg3.z, sdot8(xv[2], wg2.z, sdot8(xv[1], wg1.z, sdot8(xv[0], wg0.z, 0))));
    int a3 = sdot8(xv[3], wg3.w, sdot8(xv[2], wg2.w, sdot8(xv[1], wg1.w, sdot8(xv[0], wg0.w, 0))));
    lmax = max(lmax, max(max(a0, a1), max(a2, a3)));
  }
  block_max_commit(max(lmax, 0), maxslot);
}

// conv1 1x1 expand 32->192 + relu via sdot8, store pass. thread = 8 outs x 8 px.
__launch_bounds__(256)
__global__ void kconv1s(const unsigned int* __restrict__ xq4, const unsigned int* __restrict__ wsu,
                        const int* __restrict__ wsi, unsigned char* __restrict__ q1) {
  __shared__ unsigned int lw[NG1 * PL];  // [g][192]
  __shared__ unsigned char lut[2176];    // conv1 acc domain [0, 2048]
#pragma unroll
  for (int k = 0; k < 3; ++k)
    lw[threadIdx.x + k * 256] = wsu[W1NOFF + threadIdx.x + k * 256];
  {
    float S1 = scl(wsi[0]) * scl(wsi[1]);
    float sh1 = fmaxf((S1 * (float)wsi[4]) / 7.0f, 1e-8f);
    for (int i = threadIdx.x; i < 2176; i += 256)
      lut[i] = (unsigned char)fminf(rintf((S1 * (float)i) / sh1), 7.0f);
  }
  __syncthreads();
  int ogb = blockIdx.x / PXB;            // 0..2
  int pxb = blockIdx.x - ogb * PXB;
  int og = threadIdx.x >> 5;             // 0..7
  int pxl = threadIdx.x & 31;
  int gp = pxb * 256 + pxl * 8;          // blocks never straddle n
  int n = gp / HW, pos = gp - n * HW;
  const unsigned int* xw = xq4 + (size_t)n * NG1 * HW + pos;
  int acc[8][8] = {};
#pragma unroll
  for (int g = 0; g < NG1; ++g) {
    uint4 xa = *(const uint4*)(xw + (size_t)g * HW);
    uint4 xb = *(const uint4*)(xw + (size_t)g * HW + 4);
    uint4 wa = *(const uint4*)&lw[g * PL + ogb * 64 + og * 8];
    uint4 wb = *(const uint4*)&lw[g * PL + ogb * 64 + og * 8 + 4];
    unsigned int xv[8] = {xa.x, xa.y, xa.z, xa.w, xb.x, xb.y, xb.z, xb.w};
    unsigned int wv[8] = {wa.x, wa.y, wa.z, wa.w, wb.x, wb.y, wb.z, wb.w};
#pragma unroll
    for (int o = 0; o < 8; ++o)
#pragma unroll
      for (int j = 0; j < 8; ++j)
        acc[o][j] = sdot8(xv[j], wv[o], acc[o][j]);
  }
  int cpb = ogb * 32 + og * 4;           // 4 ch-pair planes
#pragma unroll
  for (int m = 0; m < 4; ++m) {
    unsigned int b0 = 0, b1 = 0;
#pragma unroll
    for (int j = 0; j < 4; ++j) {
      int i0 = max(acc[2 * m][j], 0);
      int i1 = max(acc[2 * m + 1][j], 0);
      b0 |= ((unsigned)(lut[i0] | (lut[i1] << 4))) << (8 * j);
      int i2 = max(acc[2 * m][4 + j], 0);
      int i3 = max(acc[2 * m + 1][4 + j], 0);
      b1 |= ((unsigned)(lut[i2] | (lut[i3] << 4))) << (8 * j);
    }
    uint2 w; w.x = b0; w.y = b1;
    *(uint2*)(q1 + ((size_t)n * CP + cpb + m) * HW + pos) = w;
  }
}

// depthwise 3x3 + relu: dual-channel sdot8 on RAW nibble bytes (no unpack).
// thread = 4 pair-planes x 2 out-rows x 8 px; branch-free edges.
template <int STORE>
__launch_bounds__(256)
__global__ void kconv2(const unsigned char* __restrict__ q1, const unsigned int* __restrict__ wsu,
                       const int* __restrict__ wsi, unsigned int* __restrict__ q2w,
                       int* __restrict__ maxslot) {
  const unsigned int* w2n = wsu + W2NOFF;
  __shared__ unsigned char lut[1024];    // index = acc + 512; negatives -> 0 (relu folded)
  if (STORE) {
    float S1 = scl(wsi[0]) * scl(wsi[1]);
    float sh1 = fmaxf((S1 * (float)wsi[4]) / 7.0f, 1e-8f);
    float S2 = sh1 * scl(wsi[2]);
    float sh2 = fmaxf((S2 * (float)wsi[5]) / 7.0f, 1e-8f);
    for (int i = threadIdx.x; i < 1024; i += 256) {
      int a = i - 512;
      lut[i] = (a <= 0) ? (unsigned char)0
                        : (unsigned char)fminf(rintf((S2 * (float)a) / sh2), 7.0f);
    }
    __syncthreads();
  }
  int gid = blockIdx.x * 256 + threadIdx.x;          // [0, NB*NG3*RT8)
  int nG = gid / RT8;
  int t  = gid - nG * RT8;
  int r2 = t / SEG8;                                 // 0..55
  int c  = t - r2 * SEG8;                            // 0..13
  int y0 = r2 * 2, x0 = c * 8;
  int n = nG / NG3, G = nG - n * NG3;
  int cp0 = G * 4;
  const unsigned char* base = q1 + ((size_t)n * CP + cp0) * HW + x0;
  int rofs[4]; bool rok[4];
#pragma unroll
  for (int R = 0; R < 4; ++R) {
    int yy = y0 - 1 + R;
    rok[R] = (unsigned)yy < (unsigned)HH;
    rofs[R] = min(max(yy, 0), HH - 1) * WID;
  }
  bool has_l = (c > 0), has_r = (c < SEG8 - 1);
  unsigned int wacc[16];
  if (STORE) {
#pragma unroll
    for (int j = 0; j < 16; ++j) wacc[j] = 0u;
  }
  int lmax = 0;
#pragma unroll
  for (int p = 0; p < 4; ++p) {
    unsigned int wc0[3], wc1[3];
    {
      const unsigned int* wp = w2n + (size_t)(cp0 + p) * 8;
      uint4 wa = *(const uint4*)wp;        // c0r0, c1r0, c0r1, c1r1
      uint2 wb = *(const uint2*)(wp + 4);  // c0r2, c1r2
      wc0[0] = wa.x; wc1[0] = wa.y; wc0[1] = wa.z; wc1[1] = wa.w;
      wc0[2] = wb.x; wc1[2] = wb.y;
    }
    const unsigned char* pb = base + (size_t)p * HW;
    int a0r0[8] = {}, a1r0[8] = {}, a0r1[8] = {}, a1r1[8] = {};
#pragma unroll
    for (int R = 0; R < 4; ++R) {
      const unsigned char* rp = pb + rofs[R];
      uint2 u = *(const uint2*)rp;
      unsigned int lwr = *(const unsigned int*)(rp - 4);
      unsigned int rwr = *(const unsigned int*)(rp + 8);
      u.x = rok[R] ? u.x : 0u;
      u.y = rok[R] ? u.y : 0u;
      lwr = (rok[R] && has_l) ? lwr : 0u;
      rwr = (rok[R] && has_r) ? rwr : 0u;
      unsigned int W[8];
      W[0] = winsh<3>(u.x, lwr);
      W[1] = u.x;
      W[2] = winsh<1>(u.y, u.x);
      W[3] = winsh<2>(u.y, u.x);
      W[4] = winsh<3>(u.y, u.x);
      W[5] = u.y;
      W[6] = winsh<1>(rwr, u.y);
      W[7] = winsh<2>(rwr, u.y);
      if (R <= 2) {
#pragma unroll
        for (int j = 0; j < 8; ++j) {
          a0r0[j] = sdot8(W[j], wc0[R], a0r0[j]);
          a1r0[j] = sdot8(W[j], wc1[R], a1r0[j]);
        }
      }
      if (R >= 1) {
#pragma unroll
        for (int j = 0; j < 8; ++j) {
          a0r1[j] = sdot8(W[j], wc0[R - 1], a0r1[j]);
          a1r1[j] = sdot8(W[j], wc1[R - 1], a1r1[j]);
        }
      }
    }
    if (!STORE) {
#pragma unroll
      for (int j = 0; j < 8; ++j) {
        lmax = max(lmax, max(a0r0[j], a1r0[j]));
        lmax = max(lmax, max(a0r1[j], a1r1[j]));
      }
    } else {
#pragma unroll
      for (int j = 0; j < 8; ++j) {
        unsigned int b0 = (unsigned)lut[512 + a0r0[j]] | ((unsigned)lut[512 + a1r0[j]] << 4);
        unsigned int b1 = (unsigned)lut[512 + a0r1[j]] | ((unsigned)lut[512 + a1r1[j]] << 4);
        wacc[j]     |= b0 << (8 * p);
        wacc[8 + j] |= b1 << (8 * p);
      }
    }
  }
  if (!STORE) {
    block_max_commit(max(lmax, 0), maxslot);
  } else {
    unsigned int* d0 = q2w + (size_t)nG * HW + (size_t)y0 * WID + x0;
    unsigned int* d1 = d0 + WID;
    uint4 o;
    o.x = wacc[0]; o.y = wacc[1]; o.z = wacc[2]; o.w = wacc[3];
    *(uint4*)d0 = o;
    o.x = wacc[4]; o.y = wacc[5]; o.z = wacc[6]; o.w = wacc[7];
    *(uint4*)(d0 + 4) = o;
    o.x = wacc[8]; o.y = wacc[9]; o.z = wacc[10]; o.w = wacc[11];
    *(uint4*)d1 = o;
    o.x = wacc[12]; o.y = wacc[13]; o.z = wacc[14]; o.w = wacc[15];
    *(uint4*)(d1 + 4) = o;
  }
}

// conv3 1x1 project 192->32 + residual via sdot8 (zero unpack). thread = 8 outs x 4 px.
__launch_bounds__(256)
__global__ void kconv3(const unsigned int* __restrict__ q2w, const float* __restrict__ x,
                       const unsigned int* __restrict__ wsu, const int* __restrict__ wsi,
                       float* __restrict__ out) {
  __shared__ unsigned int lw[NG3 * COUT];  // 3 KB, [g][32]
#pragma unroll
  for (int k = 0; k < 3; ++k)
    lw[threadIdx.x + k * 256] = wsu[W3NOFF + threadIdx.x + k * 256];
  float S1 = scl(wsi[0]) * scl(wsi[1]);
  float sh1 = fmaxf((S1 * (float)wsi[4]) / 7.0f, 1e-8f);
  float S2 = sh1 * scl(wsi[2]);
  float sh2 = fmaxf((S2 * (float)wsi[5]) / 7.0f, 1e-8f);
  float S3 = sh2 * scl(wsi[3]);
  __syncthreads();
  int og = threadIdx.x >> 6;             // 0..3 (8 outs each)
  int lane = threadIdx.x & 63;
  int gp = blockIdx.x * 256 + lane * 4;  // blocks never straddle n
  int n = gp / HW, pos = gp - n * HW;
  const unsigned int* qp = q2w + (size_t)n * NG3 * HW + pos;
  int acc[8][4] = {};
#pragma unroll 4
  for (int g = 0; g < NG3; ++g) {
    uint4 qv = *(const uint4*)(qp + (size_t)g * HW);
    uint4 wa = *(const uint4*)&lw[g * COUT + og * 8];
    uint4 wb = *(const uint4*)&lw[g * COUT + og * 8 + 4];
    unsigned int pv[4] = {qv.x, qv.y, qv.z, qv.w};
    unsigned int wv[8] = {wa.x, wa.y, wa.z, wa.w, wb.x, wb.y, wb.z, wb.w};
#pragma unroll
    for (int o = 0; o < 8; ++o)
#pragma unroll
      for (int j = 0; j < 4; ++j)
        acc[o][j] = sdot8(pv[j], wv[o], acc[o][j]);
  }
  int ob = og * 8;
#pragma unroll
  for (int o = 0; o < 8; ++o) {
    const float* xp = x + ((size_t)n * COUT + ob + o) * HW + pos;
    float* op = out + ((size_t)n * COUT + ob + o) * HW + pos;
    float4 xv = *(const float4*)xp;
    float4 r;
    r.x = fmaf(S3, (float)acc[o][0], xv.x);
    r.y = fmaf(S3, (float)acc[o][1], xv.y);
    r.z = fmaf(S3, (float)acc[o][2], xv.z);
    r.w = fmaf(S3, (float)acc[o][3], xv.w);
    *(float4*)op = r;
  }
}

extern "C" void kernel_launch(void* const* d_in, const int* in_sizes, int n_in,
                              void* d_out, int out_size, void* d_ws, size_t ws_size,
                              hipStream_t stream) {
  const float* x  = (const float*)d_in[0];
  const float* w1 = (const float*)d_in[1];
  const float* w2 = (const float*)d_in[2];
  const float* w3 = (const float*)d_in[3];
  float* out = (float*)d_out;

  int* wsi = (int*)d_ws;
  unsigned int* wsu = (unsigned int*)d_ws;
  unsigned char* q1 = (unsigned char*)d_ws + Q1OFF_BYTES;
  unsigned int* q2w = (unsigned int*)(q1 + QBYTES);
  // xq4 (6.4 MB nibble words) lives in d_out's front; consumed by kconv1s,
  // then kconv3 (sole final writer) overwrites the whole out buffer.
  unsigned int* xq4 = (unsigned int*)d_out;

  hipMemsetAsync(d_ws, 0, 64, stream);   // zero atomic-max slots + last-block counter

  int n4 = in_sizes[0] / 4;
  kmax_prep<<<1027, 256, 0, stream>>>(x, n4, w1, w2, w3, wsi, wsu);
  kqx1<<<PXB, 256, 0, stream>>>(x, wsu, wsi, xq4, wsi + 4);
  kconv1s<<<3 * PXB, 256, 0, stream>>>(xq4, wsu, wsi, q1);

  int nblk2 = NB * NG3 * RT8 / 256;                // 2352
  kconv2<0><<<nblk2, 256, 0, stream>>>(q1, wsu, wsi, q2w, wsi + 5);
  kconv2<1><<<nblk2, 256, 0, stream>>>(q1, wsu, wsi, q2w, wsi + 5);

  kconv3<<<NB * HW / 256, 256, 0, stream>>>(q2w, x, wsu, wsi, out);
}

// Round 15
// 159.786 us; speedup vs baseline: 1.5792x; 1.5792x over previous
//
#include <hip/hip_runtime.h>

#define NB   32
#define CIN  32
#define PL   192
#define CP   96        // channel pairs (PL/2)
#define NG1  4         // 8-ch groups in conv1 input (32/8)
#define NG3  24        // 8-ch groups in conv3 input (192/8)
#define HH   112
#define WID  112
#define HW   12544     // 112*112
#define COUT 32
#define PXB  1568      // NB*HW/256
#define SEG8 14        // WID/8
#define RT8  784       // (HH/2)*(WID/8) row-pair x 8px tiles per (n,G)

// ws u32-offset layout
#define W2NOFF 64                       // 768 u32: per ch-pair 8 dwords {c0r0,c1r0,c0r1,c1r1,c0r2,c1r2,0,0}
#define W1NOFF (W2NOFF + CP*8)          // 768 u32: w1 8-ch nibble words [g=4][192]
#define W3NOFF (W1NOFF + NG1*PL)        // 768 u32: w3 8-ch nibble words [g=24][32]
#define Q1OFF_BYTES 65536
#define QBYTES ((size_t)NB*CP*HW)       // 38,535,168 bytes per packed tensor
// scalars: wsi[0..3]=absmax bits x,w1,w2,w3; wsi[4]=conv1 int max; wsi[5]=conv2 int max

__device__ __forceinline__ int sdot8(unsigned int a, unsigned int b, int c) {
#if defined(__has_builtin) && __has_builtin(__builtin_amdgcn_sdot8)
  return __builtin_amdgcn_sdot8((int)a, (int)b, c, false);
#else
#pragma unroll
  for (int i = 0; i < 8; ++i)
    c += ((int)(a << (28 - 4 * i)) >> 28) * ((int)(b << (28 - 4 * i)) >> 28);
  return c;
#endif
}

// 4-byte sliding window: ((lo>>8*SH)|(hi<<(32-8*SH))) via v_perm
template <int SH>
__device__ __forceinline__ unsigned int winsh(unsigned int hi, unsigned int lo) {
#if defined(__has_builtin) && __has_builtin(__builtin_amdgcn_perm)
  const unsigned int sel = (SH == 1) ? 0x04030201u : (SH == 2) ? 0x05040302u : 0x06050403u;
  return __builtin_amdgcn_perm(hi, lo, sel);
#else
  return (lo >> (8 * SH)) | (hi << (32 - 8 * SH));
#endif
}

__device__ __forceinline__ float quant87(float v, float s) {
  return fminf(fmaxf(rintf(v / s), -8.0f), 7.0f);
}

__device__ __forceinline__ float scl(int bits) {
  return fmaxf(__int_as_float(bits) / 7.0f, 1e-8f);
}

// block-level int max -> single conditional atomic (monotone max: race-safe)
__device__ __forceinline__ void block_max_commit(int lmax, int* __restrict__ slot) {
  __shared__ int red[4];
  for (int o = 32; o; o >>= 1) lmax = max(lmax, __shfl_down(lmax, o));
  if ((threadIdx.x & 63) == 0) red[threadIdx.x >> 6] = lmax;
  __syncthreads();
  if (threadIdx.x == 0) {
    int m = max(max(red[0], red[1]), max(red[2], red[3]));
    int cur = *(const volatile int*)slot;
    if (m > cur) atomicMax(slot, m);
  }
}

// merged absmax: blocks 0..1023 -> x; 1024..1026 -> w1/w2/w3
__global__ void kmax_all(const float* __restrict__ x, int n4,
                         const float* __restrict__ w1, const float* __restrict__ w2,
                         const float* __restrict__ w3, int* __restrict__ wsi) {
  float m = 0.f;
  int slot;
  if (blockIdx.x < 1024) {
    const float4* x4 = (const float4*)x;
    for (int i = blockIdx.x * blockDim.x + threadIdx.x; i < n4; i += 1024 * blockDim.x) {
      float4 v = x4[i];
      m = fmaxf(fmaxf(fabsf(v.x), fabsf(v.y)), fmaxf(fmaxf(fabsf(v.z), fabsf(v.w)), m));
    }
    slot = 0;
  } else {
    const float* p; int n;
    int w = blockIdx.x - 1024;
    if (w == 0)      { p = w1; n = PL * CIN; }
    else if (w == 1) { p = w2; n = PL * 9; }
    else             { p = w3; n = COUT * PL; }
    for (int i = threadIdx.x; i < n; i += blockDim.x) m = fmaxf(m, fabsf(p[i]));
    slot = 1 + w;
  }
  block_max_commit(__float_as_int(m), wsi + slot);   // non-negative: int cmp == float cmp
}

// one block: quantize all weights into ws tables (divides amortized once)
__global__ void kprep(const float* __restrict__ w1, const float* __restrict__ w2,
                      const float* __restrict__ w3, unsigned int* __restrict__ wsu) {
  const int* wsi = (const int*)wsu;
  float sw1 = scl(wsi[1]);
  float sw2 = scl(wsi[2]);
  float sw3 = scl(wsi[3]);
  // w1 8-ch nibble words [g][192]
  for (int i = threadIdx.x; i < NG1 * PL; i += blockDim.x) {
    int g = i / PL, o = i - g * PL;
    unsigned int wrd = 0;
    for (int j = 0; j < 8; ++j)
      wrd |= ((unsigned)((int)quant87(w1[o * CIN + 8 * g + j], sw1) & 15)) << (4 * j);
    wsu[W1NOFF + i] = wrd;
  }
  // w2 nibble-slotted dual-channel row words
  for (int cp = threadIdx.x; cp < CP; cp += blockDim.x) {
    unsigned int d[8];
    for (int R = 0; R < 3; ++R) {
      int a0 = (int)quant87(w2[(2 * cp) * 9 + 3 * R],     sw2) & 15;
      int a1 = (int)quant87(w2[(2 * cp) * 9 + 3 * R + 1], sw2) & 15;
      int a2 = (int)quant87(w2[(2 * cp) * 9 + 3 * R + 2], sw2) & 15;
      int b0 = (int)quant87(w2[(2 * cp + 1) * 9 + 3 * R],     sw2) & 15;
      int b1 = (int)quant87(w2[(2 * cp + 1) * 9 + 3 * R + 1], sw2) & 15;
      int b2 = (int)quant87(w2[(2 * cp + 1) * 9 + 3 * R + 2], sw2) & 15;
      d[2 * R]     = (unsigned)(a0 | (a1 << 8) | (a2 << 16));
      d[2 * R + 1] = (unsigned)((b0 << 4) | (b1 << 12) | (b2 << 20));
    }
    d[6] = 0u; d[7] = 0u;
    for (int k = 0; k < 8; ++k) wsu[W2NOFF + cp * 8 + k] = d[k];
  }
  // w3 8-ch nibble words [g][32]
  for (int i = threadIdx.x; i < NG3 * COUT; i += blockDim.x) {
    int g = i / COUT, o = i - g * COUT;
    unsigned int wrd = 0;
    for (int j = 0; j < 8; ++j)
      wrd |= ((unsigned)((int)quant87(w3[o * PL + 8 * g + j], sw3) & 15)) << (4 * j);
    wsu[W3NOFF + i] = wrd;
  }
}

// fused: quantize x (1 px x 32 ch, in regs) -> write xq4 + conv1 global max.
// w1 from the prepped table (no divides beyond the 32 x-quants).
__launch_bounds__(256)
__global__ void kqx1(const float* __restrict__ x, const unsigned int* __restrict__ wsu,
                     int* __restrict__ wsi, unsigned int* __restrict__ xq4,
                     int* __restrict__ maxslot) {
  __shared__ unsigned int lw[NG1 * PL];   // [g][192]
  float sx = scl(wsi[0]);
#pragma unroll
  for (int k = 0; k < 3; ++k)
    lw[threadIdx.x + k * 256] = wsu[W1NOFF + threadIdx.x + k * 256];
  __syncthreads();
  int gp = blockIdx.x * 256 + threadIdx.x;   // blocks never straddle n
  int n = gp / HW, pos = gp - n * HW;
  const float* xp = x + (size_t)n * CIN * HW + pos;
  unsigned int xv[NG1];
#pragma unroll
  for (int g = 0; g < NG1; ++g) {
    unsigned int wrd = 0;
#pragma unroll
    for (int j = 0; j < 8; ++j) {
      float v = xp[(size_t)(8 * g + j) * HW];
      wrd |= ((unsigned)((int)quant87(v, sx) & 15)) << (4 * j);
    }
    xv[g] = wrd;
    xq4[((size_t)n * NG1 + g) * HW + pos] = wrd;
  }
  int lmax = 0;
#pragma unroll 4
  for (int o = 0; o < PL; o += 4) {
    uint4 wg0 = *(const uint4*)&lw[o];
    uint4 wg1 = *(const uint4*)&lw[PL + o];
    uint4 wg2 = *(const uint4*)&lw[2 * PL + o];
    uint4 wg3 = *(const uint4*)&lw[3 * PL + o];
    int a0 = sdot8(xv[3], wg3.x, sdot8(xv[2], wg2.x, sdot8(xv[1], wg1.x, sdot8(xv[0], wg0.x, 0))));
    int a1 = sdot8(xv[3], wg3.y, sdot8(xv[2], wg2.y, sdot8(xv[1], wg1.y, sdot8(xv[0], wg0.y, 0))));
    int a2 = sdot8(xv[3], wg3.z, sdot8(xv[2], wg2.z, sdot8(xv[1], wg1.z, sdot8(xv[0], wg0.z, 0))));
    int a3 = sdot8(xv[3], wg3.w, sdot8(xv[2], wg2.w, sdot8(xv[1], wg1.w, sdot8(xv[0], wg0.w, 0))));
    lmax = max(lmax, max(max(a0, a1), max(a2, a3)));
  }
  block_max_commit(max(lmax, 0), maxslot);
}

// conv1 1x1 expand 32->192 + relu via sdot8, store pass. thread = 8 outs x 8 px.
__launch_bounds__(256)
__global__ void kconv1s(const unsigned int* __restrict__ xq4, const unsigned int* __restrict__ wsu,
                        const int* __restrict__ wsi, unsigned char* __restrict__ q1) {
  __shared__ unsigned int lw[NG1 * PL];  // [g][192]
  __shared__ unsigned char lut[2176];    // conv1 acc domain [0, 2048]
#pragma unroll
  for (int k = 0; k < 3; ++k)
    lw[threadIdx.x + k * 256] = wsu[W1NOFF + threadIdx.x + k * 256];
  {
    float S1 = scl(wsi[0]) * scl(wsi[1]);
    float sh1 = fmaxf((S1 * (float)wsi[4]) / 7.0f, 1e-8f);
    for (int i = threadIdx.x; i < 2176; i += 256)
      lut[i] = (unsigned char)fminf(rintf((S1 * (float)i) / sh1), 7.0f);
  }
  __syncthreads();
  int ogb = blockIdx.x / PXB;            // 0..2
  int pxb = blockIdx.x - ogb * PXB;
  int og = threadIdx.x >> 5;             // 0..7
  int pxl = threadIdx.x & 31;
  int gp = pxb * 256 + pxl * 8;          // blocks never straddle n
  int n = gp / HW, pos = gp - n * HW;
  const unsigned int* xw = xq4 + (size_t)n * NG1 * HW + pos;
  int acc[8][8] = {};
#pragma unroll
  for (int g = 0; g < NG1; ++g) {
    uint4 xa = *(const uint4*)(xw + (size_t)g * HW);
    uint4 xb = *(const uint4*)(xw + (size_t)g * HW + 4);
    uint4 wa = *(const uint4*)&lw[g * PL + ogb * 64 + og * 8];
    uint4 wb = *(const uint4*)&lw[g * PL + ogb * 64 + og * 8 + 4];
    unsigned int xv[8] = {xa.x, xa.y, xa.z, xa.w, xb.x, xb.y, xb.z, xb.w};
    unsigned int wv[8] = {wa.x, wa.y, wa.z, wa.w, wb.x, wb.y, wb.z, wb.w};
#pragma unroll
    for (int o = 0; o < 8; ++o)
#pragma unroll
      for (int j = 0; j < 8; ++j)
        acc[o][j] = sdot8(xv[j], wv[o], acc[o][j]);
  }
  int cpb = ogb * 32 + og * 4;           // 4 ch-pair planes
#pragma unroll
  for (int m = 0; m < 4; ++m) {
    unsigned int b0 = 0, b1 = 0;
#pragma unroll
    for (int j = 0; j < 4; ++j) {
      int i0 = max(acc[2 * m][j], 0);
      int i1 = max(acc[2 * m + 1][j], 0);
      b0 |= ((unsigned)(lut[i0] | (lut[i1] << 4))) << (8 * j);
      int i2 = max(acc[2 * m][4 + j], 0);
      int i3 = max(acc[2 * m + 1][4 + j], 0);
      b1 |= ((unsigned)(lut[i2] | (lut[i3] << 4))) << (8 * j);
    }
    uint2 w; w.x = b0; w.y = b1;
    *(uint2*)(q1 + ((size_t)n * CP + cpb + m) * HW + pos) = w;
  }
}

// depthwise 3x3 + relu: dual-channel sdot8 on RAW nibble bytes (no unpack).
// thread = 4 pair-planes x 2 out-rows x 8 px; branch-free edges.
template <int STORE>
__launch_bounds__(256)
__global__ void kconv2(const unsigned char* __restrict__ q1, const unsigned int* __restrict__ wsu,
                       const int* __restrict__ wsi, unsigned int* __restrict__ q2w,
                       int* __restrict__ maxslot) {
  const unsigned int* w2n = wsu + W2NOFF;
  __shared__ unsigned char lut[1024];    // index = acc + 512; negatives -> 0 (relu folded)
  if (STORE) {
    float S1 = scl(wsi[0]) * scl(wsi[1]);
    float sh1 = fmaxf((S1 * (float)wsi[4]) / 7.0f, 1e-8f);
    float S2 = sh1 * scl(wsi[2]);
    float sh2 = fmaxf((S2 * (float)wsi[5]) / 7.0f, 1e-8f);
    for (int i = threadIdx.x; i < 1024; i += 256) {
      int a = i - 512;
      lut[i] = (a <= 0) ? (unsigned char)0
                        : (unsigned char)fminf(rintf((S2 * (float)a) / sh2), 7.0f);
    }
    __syncthreads();
  }
  int gid = blockIdx.x * 256 + threadIdx.x;          // [0, NB*NG3*RT8)
  int nG = gid / RT8;
  int t  = gid - nG * RT8;
  int r2 = t / SEG8;                                 // 0..55
  int c  = t - r2 * SEG8;                            // 0..13
  int y0 = r2 * 2, x0 = c * 8;
  int n = nG / NG3, G = nG - n * NG3;
  int cp0 = G * 4;
  const unsigned char* base = q1 + ((size_t)n * CP + cp0) * HW + x0;
  int rofs[4]; bool rok[4];
#pragma unroll
  for (int R = 0; R < 4; ++R) {
    int yy = y0 - 1 + R;
    rok[R] = (unsigned)yy < (unsigned)HH;
    rofs[R] = min(max(yy, 0), HH - 1) * WID;
  }
  bool has_l = (c > 0), has_r = (c < SEG8 - 1);
  unsigned int wacc[16];
  if (STORE) {
#pragma unroll
    for (int j = 0; j < 16; ++j) wacc[j] = 0u;
  }
  int lmax = 0;
#pragma unroll
  for (int p = 0; p < 4; ++p) {
    unsigned int wc0[3], wc1[3];
    {
      const unsigned int* wp = w2n + (size_t)(cp0 + p) * 8;
      uint4 wa = *(const uint4*)wp;        // c0r0, c1r0, c0r1, c1r1
      uint2 wb = *(const uint2*)(wp + 4);  // c0r2, c1r2
      wc0[0] = wa.x; wc1[0] = wa.y; wc0[1] = wa.z; wc1[1] = wa.w;
      wc0[2] = wb.x; wc1[2] = wb.y;
    }
    const unsigned char* pb = base + (size_t)p * HW;
    int a0r0[8] = {}, a1r0[8] = {}, a0r1[8] = {}, a1r1[8] = {};
#pragma unroll
    for (int R = 0; R < 4; ++R) {
      const unsigned char* rp = pb + rofs[R];
      uint2 u = *(const uint2*)rp;
      unsigned int lwr = *(const unsigned int*)(rp - 4);
      unsigned int rwr = *(const unsigned int*)(rp + 8);
      u.x = rok[R] ? u.x : 0u;
      u.y = rok[R] ? u.y : 0u;
      lwr = (rok[R] && has_l) ? lwr : 0u;
      rwr = (rok[R] && has_r) ? rwr : 0u;
      unsigned int W[8];
      W[0] = winsh<3>(u.x, lwr);
      W[1] = u.x;
      W[2] = winsh<1>(u.y, u.x);
      W[3] = winsh<2>(u.y, u.x);
      W[4] = winsh<3>(u.y, u.x);
      W[5] = u.y;
      W[6] = winsh<1>(rwr, u.y);
      W[7] = winsh<2>(rwr, u.y);
      if (R <= 2) {
#pragma unroll
        for (int j = 0; j < 8; ++j) {
          a0r0[j] = sdot8(W[j], wc0[R], a0r0[j]);
          a1r0[j] = sdot8(W[j], wc1[R], a1r0[j]);
        }
      }
      if (R >= 1) {
#pragma unroll
        for (int j = 0; j < 8; ++j) {
          a0r1[j] = sdot8(W[j], wc0[R - 1], a0r1[j]);
          a1r1[j] = sdot8(W[j], wc1[R - 1], a1r1[j]);
        }
      }
    }
    if (!STORE) {
#pragma unroll
      for (int j = 0; j < 8; ++j) {
        lmax = max(lmax, max(a0r0[j], a1r0[j]));
        lmax = max(lmax, max(a0r1[j], a1r1[j]));
      }
    } else {
#pragma unroll
      for (int j = 0; j < 8; ++j) {
        unsigned int b0 = (unsigned)lut[512 + a0r0[j]] | ((unsigned)lut[512 + a1r0[j]] << 4);
        unsigned int b1 = (unsigned)lut[512 + a0r1[j]] | ((unsigned)lut[512 + a1r1[j]] << 4);
        wacc[j]     |= b0 << (8 * p);
        wacc[8 + j] |= b1 << (8 * p);
      }
    }
  }
  if (!STORE) {
    block_max_commit(max(lmax, 0), maxslot);
  } else {
    unsigned int* d0 = q2w + (size_t)nG * HW + (size_t)y0 * WID + x0;
    unsigned int* d1 = d0 + WID;
    uint4 o;
    o.x = wacc[0]; o.y = wacc[1]; o.z = wacc[2]; o.w = wacc[3];
    *(uint4*)d0 = o;
    o.x = wacc[4]; o.y = wacc[5]; o.z = wacc[6]; o.w = wacc[7];
    *(uint4*)(d0 + 4) = o;
    o.x = wacc[8]; o.y = wacc[9]; o.z = wacc[10]; o.w = wacc[11];
    *(uint4*)d1 = o;
    o.x = wacc[12]; o.y = wacc[13]; o.z = wacc[14]; o.w = wacc[15];
    *(uint4*)(d1 + 4) = o;
  }
}

// conv3 1x1 project 192->32 + residual via sdot8 (zero unpack). thread = 8 outs x 4 px.
__launch_bounds__(256)
__global__ void kconv3(const unsigned int* __restrict__ q2w, const float* __restrict__ x,
                       const unsigned int* __restrict__ wsu, const int* __restrict__ wsi,
                       float* __restrict__ out) {
  __shared__ unsigned int lw[NG3 * COUT];  // 3 KB, [g][32]
#pragma unroll
  for (int k = 0; k < 3; ++k)
    lw[threadIdx.x + k * 256] = wsu[W3NOFF + threadIdx.x + k * 256];
  float S1 = scl(wsi[0]) * scl(wsi[1]);
  float sh1 = fmaxf((S1 * (float)wsi[4]) / 7.0f, 1e-8f);
  float S2 = sh1 * scl(wsi[2]);
  float sh2 = fmaxf((S2 * (float)wsi[5]) / 7.0f, 1e-8f);
  float S3 = sh2 * scl(wsi[3]);
  __syncthreads();
  int og = threadIdx.x >> 6;             // 0..3 (8 outs each)
  int lane = threadIdx.x & 63;
  int gp = blockIdx.x * 256 + lane * 4;  // blocks never straddle n
  int n = gp / HW, pos = gp - n * HW;
  const unsigned int* qp = q2w + (size_t)n * NG3 * HW + pos;
  int acc[8][4] = {};
#pragma unroll 4
  for (int g = 0; g < NG3; ++g) {
    uint4 qv = *(const uint4*)(qp + (size_t)g * HW);
    uint4 wa = *(const uint4*)&lw[g * COUT + og * 8];
    uint4 wb = *(const uint4*)&lw[g * COUT + og * 8 + 4];
    unsigned int pv[4] = {qv.x, qv.y, qv.z, qv.w};
    unsigned int wv[8] = {wa.x, wa.y, wa.z, wa.w, wb.x, wb.y, wb.z, wb.w};
#pragma unroll
    for (int o = 0; o < 8; ++o)
#pragma unroll
      for (int j = 0; j < 4; ++j)
        acc[o][j] = sdot8(pv[j], wv[o], acc[o][j]);
  }
  int ob = og * 8;
#pragma unroll
  for (int o = 0; o < 8; ++o) {
    const float* xp = x + ((size_t)n * COUT + ob + o) * HW + pos;
    float* op = out + ((size_t)n * COUT + ob + o) * HW + pos;
    float4 xv = *(const float4*)xp;
    float4 r;
    r.x = fmaf(S3, (float)acc[o][0], xv.x);
    r.y = fmaf(S3, (float)acc[o][1], xv.y);
    r.z = fmaf(S3, (float)acc[o][2], xv.z);
    r.w = fmaf(S3, (float)acc[o][3], xv.w);
    *(float4*)op = r;
  }
}

extern "C" void kernel_launch(void* const* d_in, const int* in_sizes, int n_in,
                              void* d_out, int out_size, void* d_ws, size_t ws_size,
                              hipStream_t stream) {
  const float* x  = (const float*)d_in[0];
  const float* w1 = (const float*)d_in[1];
  const float* w2 = (const float*)d_in[2];
  const float* w3 = (const float*)d_in[3];
  float* out = (float*)d_out;

  int* wsi = (int*)d_ws;
  unsigned int* wsu = (unsigned int*)d_ws;
  unsigned char* q1 = (unsigned char*)d_ws + Q1OFF_BYTES;
  unsigned int* q2w = (unsigned int*)(q1 + QBYTES);
  // xq4 (6.4 MB nibble words) lives in d_out's front; consumed by kconv1s,
  // then kconv3 (sole final writer) overwrites the whole out buffer.
  unsigned int* xq4 = (unsigned int*)d_out;

  hipMemsetAsync(d_ws, 0, 64, stream);   // zero the 6 atomic-max slots

  int n4 = in_sizes[0] / 4;
  kmax_all<<<1027, 256, 0, stream>>>(x, n4, w1, w2, w3, wsi);
  kprep<<<1, 256, 0, stream>>>(w1, w2, w3, wsu);
  kqx1<<<PXB, 256, 0, stream>>>(x, wsu, wsi, xq4, wsi + 4);
  kconv1s<<<3 * PXB, 256, 0, stream>>>(xq4, wsu, wsi, q1);

  int nblk2 = NB * NG3 * RT8 / 256;                // 2352
  kconv2<0><<<nblk2, 256, 0, stream>>>(q1, wsu, wsi, q2w, wsi + 5);
  kconv2<1><<<nblk2, 256, 0, stream>>>(q1, wsu, wsi, q2w, wsi + 5);

  kconv3<<<NB * HW / 256, 256, 0, stream>>>(q2w, x, wsu, wsi, out);
}